// Round 8
// baseline (247.031 us; speedup 1.0000x reference)
//
#include <hip/hip_runtime.h>

#define NH   8
#define SEQ  2048
#define DIM  512
#define EMB  512
#define DH   64
#define HALF 128
#define QT   16
#define KW   272          // QT + 2*HALF
#define SCS  276          // Sc row stride (f32)
#define GRID 512

typedef __attribute__((ext_vector_type(8))) short short8;
typedef __attribute__((ext_vector_type(4))) float f32x4;

__device__ __forceinline__ unsigned short f2bf(float f) {
    unsigned int u = __float_as_uint(f);
    return (unsigned short)((u + 0x7fffu + ((u >> 16) & 1u)) >> 16);
}

__device__ __forceinline__ void gload_lds16(const void* g, void* l) {
    __builtin_amdgcn_global_load_lds((__attribute__((address_space(1))) void*)g,
                                     (__attribute__((address_space(3))) void*)l,
                                     16, 0, 0);
}

// monotonic grid barrier: every block adds 1, waits until count >= tgt.
// AGENT-scope acq_rel gives cross-XCD L2 writeback/invalidate.
__device__ __forceinline__ void grid_barrier(unsigned* c, unsigned tgt) {
    __syncthreads();
    if (threadIdx.x == 0) {
        __hip_atomic_fetch_add(c, 1u, __ATOMIC_ACQ_REL, __HIP_MEMORY_SCOPE_AGENT);
        while (__hip_atomic_load(c, __ATOMIC_ACQUIRE, __HIP_MEMORY_SCOPE_AGENT) < tgt)
            __builtin_amdgcn_s_sleep(2);
    }
    __syncthreads();
}

// ---- phase 1: one 128x64 qkv tile (identical math to R7 gemm_qkv) ----
__device__ __forceinline__ void qkv_tile(int bm, int bn,
        const unsigned short* __restrict__ A, const unsigned short* __restrict__ B,
        const float* __restrict__ bias, unsigned short* __restrict__ qkvh,
        unsigned short* __restrict__ vT, char* smemc, int t) {
    constexpr int BM = 128, BN = 64, BK = 64;
    unsigned short* SM = (unsigned short*)smemc;
    unsigned short* As = SM;            // [128][64] swizzled
    unsigned short* Bs = SM + BM * BK;  // [64][64]  swizzled
    const int lane = t & 63, wid = t >> 6;
    const int wr = wid >> 1, wc = wid & 1;
    const int lr = lane & 15, lg = lane >> 4;

    f32x4 acc[4][2];
    #pragma unroll
    for (int m = 0; m < 4; ++m)
        #pragma unroll
        for (int n = 0; n < 2; ++n)
            acc[m][n] = (f32x4){0.f, 0.f, 0.f, 0.f};

    for (int kt = 0; kt < DIM; kt += BK) {
        #pragma unroll
        for (int off = 0; off < BM * BK; off += 2048) {
            const int e = off + t * 8, r = e >> 6, c4 = (e & 63) >> 3;
            const int gc = (c4 ^ (r & 7)) << 3;
            gload_lds16(A + (size_t)(bm + r) * DIM + kt + gc, &As[e]);
        }
        #pragma unroll
        for (int off = 0; off < BN * BK; off += 2048) {
            const int e = off + t * 8, r = e >> 6, c4 = (e & 63) >> 3;
            const int gc = (c4 ^ (r & 7)) << 3;
            gload_lds16(B + (size_t)(bn + r) * DIM + kt + gc, &Bs[e]);
        }
        __syncthreads();
        short8 af[2][4], bf[2][2];
        #pragma unroll
        for (int kk = 0; kk < 2; ++kk) {
            #pragma unroll
            for (int m = 0; m < 4; ++m) {
                const int row = wr * 64 + m * 16 + lr;
                af[kk][m] = *(const short8*)&As[row * 64 + (((kk * 4 + lg) ^ (row & 7)) << 3)];
            }
            #pragma unroll
            for (int n = 0; n < 2; ++n) {
                const int row = wc * 32 + n * 16 + lr;
                bf[kk][n] = *(const short8*)&Bs[row * 64 + (((kk * 4 + lg) ^ (row & 7)) << 3)];
            }
        }
        #pragma unroll
        for (int kk = 0; kk < 2; ++kk)
            #pragma unroll
            for (int m = 0; m < 4; ++m)
                #pragma unroll
                for (int n = 0; n < 2; ++n)
                    acc[m][n] = __builtin_amdgcn_mfma_f32_16x16x32_bf16(af[kk][m], bf[kk][n], acc[m][n], 0, 0, 0);
        __syncthreads();
    }

    // epilogue: acc -> Tr[128][72] bf16 (reuse SM), then packed stores
    unsigned short* Tr = SM;
    #pragma unroll
    for (int n = 0; n < 2; ++n) {
        const int cl = wc * 32 + n * 16 + lr;
        const float bv = bias[bn + cl];
        #pragma unroll
        for (int m = 0; m < 4; ++m)
            #pragma unroll
            for (int r = 0; r < 4; ++r)
                Tr[(wr * 64 + m * 16 + lg * 4 + r) * 72 + cl] = f2bf(acc[m][n][r] + bv);
    }
    __syncthreads();

    const int h = bn / 192, ty = (bn >> 6) % 3;
    const int bb = bm >> 11, s0 = bm & 2047;
    if (ty < 2) {   // Q,K: contiguous [s][d] rows
        unsigned short* plane = qkvh + (((size_t)(bb * NH + h) * 3 + ty) * SEQ) * DH;
        const int s = t >> 1, hf = (t & 1) * 32;
        unsigned short* dst = plane + (size_t)(s0 + s) * DH + hf;
        #pragma unroll
        for (int k8 = 0; k8 < 4; ++k8)
            *(short8*)&dst[k8 * 8] = *(const short8*)&Tr[s * 72 + hf + k8 * 8];
    } else {        // V: transposed packed [d][s] stores
        const int d = t >> 2, pp = t & 3;
        unsigned short* vrow = vT + ((size_t)(bb * NH + h) * DH + d) * SEQ + s0 + pp * 32;
        #pragma unroll
        for (int k8 = 0; k8 < 4; ++k8) {
            alignas(16) unsigned short tmp[8];
            #pragma unroll
            for (int k = 0; k < 8; ++k) tmp[k] = Tr[(pp * 32 + k8 * 8 + k) * 72 + d];
            *(short8*)&vrow[k8 * 8] = *(short8*)tmp;
        }
    }
    __syncthreads();   // protect Tr/SM before next tile restages
}

// ---- phase 2: one (bh, 16-query) attention tile (identical to R7 attn) ----
__device__ __forceinline__ void attn_tile(int bh, int qt,
        const unsigned short* __restrict__ qkvh, const unsigned short* __restrict__ vT,
        const int* __restrict__ pad, unsigned short* __restrict__ Yb,
        char* smemc, int t) {
    const int b = bh >> 3, h = bh & 7;
    const int i0 = qt * QT, kb = i0 - HALF;
    const int lane = t & 63, w = t >> 6;
    const int lr = lane & 15, lg = lane >> 4;
    float* Sc = (float*)smemc;

    const unsigned short* Qg = qkvh + ((size_t)bh * 3 + 0) * SEQ * DH;
    const unsigned short* Kg = qkvh + ((size_t)bh * 3 + 1) * SEQ * DH;
    const unsigned short* vTg = vT + (size_t)bh * DH * SEQ;
    const int* padb = pad + b * SEQ;

    short8 qf[2];
    #pragma unroll
    for (int kk = 0; kk < 2; ++kk)
        qf[kk] = *(const short8*)&Qg[(size_t)(i0 + lr) * DH + kk * 32 + lg * 8];

    const int k0 = w * 16;
    #pragma unroll
    for (int c = 0; c < 5; ++c) {
        const int nc = (c < 4) ? 64 : 16;
        if (k0 < nc) {
            const int jl = c * 64 + k0 + lr;
            const int j = kb + jl;
            const int jc = j < 0 ? 0 : (j > SEQ - 1 ? SEQ - 1 : j);
            const int kv = (j >= 0 && j < SEQ) ? padb[j] : 0;
            f32x4 a0 = (f32x4){0.f, 0.f, 0.f, 0.f};
            #pragma unroll
            for (int kk = 0; kk < 2; ++kk) {
                const short8 bfr = *(const short8*)&Kg[(size_t)jc * DH + kk * 32 + lg * 8];
                a0 = __builtin_amdgcn_mfma_f32_16x16x32_bf16(qf[kk], bfr, a0, 0, 0, 0);
            }
            #pragma unroll
            for (int r = 0; r < 4; ++r) {
                const int q0 = lg * 4 + r;
                const bool ok = kv && (jl >= q0) && (jl <= q0 + 2 * HALF);
                Sc[q0 * SCS + jl] = ok ? a0[r] * 0.125f : -1e30f;
            }
        }
    }
    __syncthreads();

    for (int r = w; r < QT; r += 4) {
        float* row = &Sc[r * SCS];
        unsigned short* prow = (unsigned short*)row;
        if (!padb[i0 + r]) {
            #pragma unroll
            for (int u = 0; u < 5; ++u) {
                const int jl = lane + 64 * u;
                if (jl < KW) prow[jl] = 0;
            }
            if (lane >= 16 && lane < 32) prow[256 + lane] = 0;
            continue;
        }
        float v[5];
        float mx = -1e30f;
        #pragma unroll
        for (int u = 0; u < 5; ++u) {
            const int jl = lane + 64 * u;
            v[u] = (jl < KW) ? row[jl] : -1e30f;
            mx = fmaxf(mx, v[u]);
        }
        #pragma unroll
        for (int off = 32; off; off >>= 1) mx = fmaxf(mx, __shfl_xor(mx, off));
        float s = 0.f;
        #pragma unroll
        for (int u = 0; u < 5; ++u) { v[u] = __expf(v[u] - mx); s += v[u]; }
        #pragma unroll
        for (int off = 32; off; off >>= 1) s += __shfl_xor(s, off);
        const float inv = 1.f / s;
        asm volatile("" ::: "memory");
        #pragma unroll
        for (int u = 0; u < 5; ++u) {
            const int jl = lane + 64 * u;
            if (jl < KW) prow[jl] = f2bf(v[u] * inv);
        }
        if (lane >= 16 && lane < 32) prow[256 + lane] = 0;
    }
    __syncthreads();

    f32x4 o0 = (f32x4){0.f, 0.f, 0.f, 0.f};
    const unsigned short* PbU = (const unsigned short*)Sc;
    const int d0 = w * 16 + lr;
    #pragma unroll
    for (int c = 0; c < 5; ++c) {
        const int nkk = (c < 4) ? 2 : 1;
        #pragma unroll
        for (int kk = 0; kk < nkk; ++kk) {
            int j0 = kb + c * 64 + kk * 32 + lg * 8;
            j0 = j0 < 0 ? 0 : (j0 > SEQ - 8 ? SEQ - 8 : j0);
            const short8 vf = *(const short8*)&vTg[(size_t)d0 * SEQ + j0];
            const short8 pf = *(const short8*)&PbU[lr * (SCS * 2) + c * 64 + kk * 32 + lg * 8];
            o0 = __builtin_amdgcn_mfma_f32_16x16x32_bf16(pf, vf, o0, 0, 0, 0);
        }
    }

    #pragma unroll
    for (int r = 0; r < 4; ++r)
        Yb[(size_t)(b * SEQ + i0 + lg * 4 + r) * EMB + h * DH + d0] = f2bf(o0[r]);
    __syncthreads();   // protect Sc before next tile rewrites scores
}

// ---- phase 3: one 64x64 out-GEMM tile (identical to R7 gemm_bf16<64,64,64,2,2>) ----
__device__ __forceinline__ void out_tile(int bm, int bn,
        const unsigned short* __restrict__ A, const unsigned short* __restrict__ B,
        const float* __restrict__ bias, float* __restrict__ C,
        char* smemc, int t) {
    constexpr int BM = 64, BN = 64, BK = 64;
    unsigned short* As = (unsigned short*)smemc;
    unsigned short* Bs = As + BM * BK;
    const int lane = t & 63, wid = t >> 6;
    const int wr = wid >> 1, wc = wid & 1;
    const int lr = lane & 15, lg = lane >> 4;

    f32x4 acc[2][2];
    #pragma unroll
    for (int m = 0; m < 2; ++m)
        #pragma unroll
        for (int n = 0; n < 2; ++n)
            acc[m][n] = (f32x4){0.f, 0.f, 0.f, 0.f};

    for (int kt = 0; kt < DIM; kt += BK) {
        #pragma unroll
        for (int off = 0; off < BM * BK; off += 2048) {
            const int e = off + t * 8, r = e >> 6, c4 = (e & 63) >> 3;
            const int gc = (c4 ^ (r & 7)) << 3;
            gload_lds16(A + (size_t)(bm + r) * DIM + kt + gc, &As[e]);
        }
        #pragma unroll
        for (int off = 0; off < BN * BK; off += 2048) {
            const int e = off + t * 8, r = e >> 6, c4 = (e & 63) >> 3;
            const int gc = (c4 ^ (r & 7)) << 3;
            gload_lds16(B + (size_t)(bn + r) * DIM + kt + gc, &Bs[e]);
        }
        __syncthreads();
        short8 af[2][2], bf[2][2];
        #pragma unroll
        for (int kk = 0; kk < 2; ++kk) {
            #pragma unroll
            for (int m = 0; m < 2; ++m) {
                const int row = wr * 32 + m * 16 + lr;
                af[kk][m] = *(const short8*)&As[row * BK + (((kk * 4 + lg) ^ (row & 7)) << 3)];
            }
            #pragma unroll
            for (int n = 0; n < 2; ++n) {
                const int row = wc * 32 + n * 16 + lr;
                bf[kk][n] = *(const short8*)&Bs[row * BK + (((kk * 4 + lg) ^ (row & 7)) << 3)];
            }
        }
        #pragma unroll
        for (int kk = 0; kk < 2; ++kk)
            #pragma unroll
            for (int m = 0; m < 2; ++m)
                #pragma unroll
                for (int n = 0; n < 2; ++n)
                    acc[m][n] = __builtin_amdgcn_mfma_f32_16x16x32_bf16(af[kk][m], bf[kk][n], acc[m][n], 0, 0, 0);
        __syncthreads();
    }

    const int orow = bm + wr * 32 + lg * 4;
    const int oc0 = bn + wc * 32 + lr;
    #pragma unroll
    for (int m = 0; m < 2; ++m)
        #pragma unroll
        for (int n = 0; n < 2; ++n) {
            const int col = oc0 + n * 16;
            const float bv = bias[col];
            #pragma unroll
            for (int r = 0; r < 4; ++r)
                C[(size_t)(orow + m * 16 + r) * EMB + col] = acc[m][n][r] + bv;
        }
}

// ---- the whole pipeline, one launch ----
__global__ __launch_bounds__(256, 2)
void mega(const float* __restrict__ x, const int* __restrict__ pad,
          const float* __restrict__ wqkv_f, const float* __restrict__ bqkv,
          const float* __restrict__ wo_f, const float* __restrict__ bo,
          float* __restrict__ out,
          unsigned short* __restrict__ qkvh, unsigned short* __restrict__ vT,
          unsigned short* __restrict__ cvtbase, unsigned* __restrict__ counter) {
    __shared__ __align__(16) char smem[24576];
    const int bid = blockIdx.x, t = threadIdx.x;

    unsigned short* xb    = cvtbase;              // [4096,512]  bf16
    unsigned short* wqkvb = cvtbase + 2097152;    // [1536,512]  bf16
    unsigned short* wob   = cvtbase + 2883584;    // [512,512]   bf16
    unsigned short* Yb    = xb;                   // xb dead after phase 1

    // phase 0: f32 -> bf16 conversions (x, Wqkv, Wo)
    for (int i = bid * 256 + t; i < 786432; i += GRID * 256) {
        const float* src; int base;
        if (i < 524288)      { src = x;      base = 0; }
        else if (i < 720896) { src = wqkv_f; base = 524288; }
        else                 { src = wo_f;   base = 720896; }
        float4 v = ((const float4*)src)[i - base];
        ((ushort4*)cvtbase)[i] = make_ushort4(f2bf(v.x), f2bf(v.y), f2bf(v.z), f2bf(v.w));
    }
    grid_barrier(counter, GRID);

    // phase 1: qkv projection, 768 tiles of 128x64
    for (int tile = bid; tile < 768; tile += GRID)
        qkv_tile((tile / 24) * 128, (tile % 24) * 64, xb, wqkvb, bqkv, qkvh, vT, smem, t);
    grid_barrier(counter, 2 * GRID);

    // phase 2: windowed attention, 2048 tiles (exactly 4 per block)
    for (int tile = bid; tile < 2048; tile += GRID)
        attn_tile(tile >> 7, tile & 127, qkvh, vT, pad, Yb, smem, t);
    grid_barrier(counter, 3 * GRID);

    // phase 3: output projection, 512 tiles of 64x64 (exactly 1 per block)
    out_tile((bid >> 3) * 64, (bid & 7) * 64, Yb, wob, bo, out, smem, t);
}

extern "C" void kernel_launch(void* const* d_in, const int* in_sizes, int n_in,
                              void* d_out, int out_size, void* d_ws, size_t ws_size,
                              hipStream_t stream) {
    const float* x    = (const float*)d_in[0];
    const int*   pad  = (const int*)d_in[1];
    const float* Wqkv = (const float*)d_in[2];
    const float* bqkv = (const float*)d_in[3];
    const float* Wo   = (const float*)d_in[4];
    const float* bo   = (const float*)d_in[5];
    float* out = (float*)d_out;

    char* p = (char*)d_ws;
    unsigned short* qkvh    = (unsigned short*)p;                   // 12.6 MB (Q,K planes)
    unsigned short* vT      = (unsigned short*)(p + 12582912);      // 4 MB
    unsigned short* cvtbase = (unsigned short*)(p + 16777216);      // 6 MB (xb|wqkvb|wob)
    unsigned*       counter = (unsigned*)(p + 23068672);

    hipMemsetAsync(counter, 0, 64, stream);
    mega<<<dim3(GRID), dim3(256), 0, stream>>>(x, pad, Wqkv, bqkv, Wo, bo,
                                               out, qkvh, vT, cvtbase, counter);
}

// Round 9
// 201.747 us; speedup vs baseline: 1.2245x; 1.2245x over previous
//
#include <hip/hip_runtime.h>

#define NH   8
#define SEQ  2048
#define DIM  512
#define EMB  512
#define DH   64
#define HALF 128
#define QT   16
#define KW   272          // QT + 2*HALF
#define SCS  276          // Sc row stride (f32)
#define GRID 512

typedef __attribute__((ext_vector_type(8))) short short8;
typedef __attribute__((ext_vector_type(4))) float f32x4;

__device__ __forceinline__ unsigned short f2bf(float f) {
    unsigned int u = __float_as_uint(f);
    return (unsigned short)((u + 0x7fffu + ((u >> 16) & 1u)) >> 16);
}

__device__ __forceinline__ void gload_lds16(const void* g, void* l) {
    __builtin_amdgcn_global_load_lds((__attribute__((address_space(1))) void*)g,
                                     (__attribute__((address_space(3))) void*)l,
                                     16, 0, 0);
}

// monotonic grid barrier. Release once (L2 writeback), spin RELAXED (no
// cache-invalidate side effect -- R8's acquire-poll invalidated the XCD L2
// every iteration and destroyed all cached state), then ONE acquire RMW.
__device__ __forceinline__ void grid_barrier(unsigned* c, unsigned tgt) {
    __syncthreads();
    if (threadIdx.x == 0) {
        __hip_atomic_fetch_add(c, 1u, __ATOMIC_RELEASE, __HIP_MEMORY_SCOPE_AGENT);
        while (__hip_atomic_load(c, __ATOMIC_RELAXED, __HIP_MEMORY_SCOPE_AGENT) < tgt)
            __builtin_amdgcn_s_sleep(8);
        __hip_atomic_fetch_add(c, 0u, __ATOMIC_ACQUIRE, __HIP_MEMORY_SCOPE_AGENT);
    }
    __syncthreads();
}

// ---- phase 1: one 128x64 qkv tile ----
__device__ __forceinline__ void qkv_tile(int bm, int bn,
        const unsigned short* __restrict__ A, const unsigned short* __restrict__ B,
        const float* __restrict__ bias, unsigned short* __restrict__ qkvh,
        unsigned short* __restrict__ vT, char* smemc, int t) {
    constexpr int BM = 128, BN = 64, BK = 64;
    unsigned short* SM = (unsigned short*)smemc;
    unsigned short* As = SM;            // [128][64] swizzled
    unsigned short* Bs = SM + BM * BK;  // [64][64]  swizzled
    const int lane = t & 63, wid = t >> 6;
    const int wr = wid >> 1, wc = wid & 1;
    const int lr = lane & 15, lg = lane >> 4;

    f32x4 acc[4][2];
    #pragma unroll
    for (int m = 0; m < 4; ++m)
        #pragma unroll
        for (int n = 0; n < 2; ++n)
            acc[m][n] = (f32x4){0.f, 0.f, 0.f, 0.f};

    for (int kt = 0; kt < DIM; kt += BK) {
        #pragma unroll
        for (int off = 0; off < BM * BK; off += 2048) {
            const int e = off + t * 8, r = e >> 6, c4 = (e & 63) >> 3;
            const int gc = (c4 ^ (r & 7)) << 3;
            gload_lds16(A + (size_t)(bm + r) * DIM + kt + gc, &As[e]);
        }
        #pragma unroll
        for (int off = 0; off < BN * BK; off += 2048) {
            const int e = off + t * 8, r = e >> 6, c4 = (e & 63) >> 3;
            const int gc = (c4 ^ (r & 7)) << 3;
            gload_lds16(B + (size_t)(bn + r) * DIM + kt + gc, &Bs[e]);
        }
        __syncthreads();
        short8 af[2][4], bf[2][2];
        #pragma unroll
        for (int kk = 0; kk < 2; ++kk) {
            #pragma unroll
            for (int m = 0; m < 4; ++m) {
                const int row = wr * 64 + m * 16 + lr;
                af[kk][m] = *(const short8*)&As[row * 64 + (((kk * 4 + lg) ^ (row & 7)) << 3)];
            }
            #pragma unroll
            for (int n = 0; n < 2; ++n) {
                const int row = wc * 32 + n * 16 + lr;
                bf[kk][n] = *(const short8*)&Bs[row * 64 + (((kk * 4 + lg) ^ (row & 7)) << 3)];
            }
        }
        #pragma unroll
        for (int kk = 0; kk < 2; ++kk)
            #pragma unroll
            for (int m = 0; m < 4; ++m)
                #pragma unroll
                for (int n = 0; n < 2; ++n)
                    acc[m][n] = __builtin_amdgcn_mfma_f32_16x16x32_bf16(af[kk][m], bf[kk][n], acc[m][n], 0, 0, 0);
        __syncthreads();
    }

    // epilogue: acc -> Tr[128][72] bf16 (reuse SM), then packed stores
    unsigned short* Tr = SM;
    #pragma unroll
    for (int n = 0; n < 2; ++n) {
        const int cl = wc * 32 + n * 16 + lr;
        const float bv = bias[bn + cl];
        #pragma unroll
        for (int m = 0; m < 4; ++m)
            #pragma unroll
            for (int r = 0; r < 4; ++r)
                Tr[(wr * 64 + m * 16 + lg * 4 + r) * 72 + cl] = f2bf(acc[m][n][r] + bv);
    }
    __syncthreads();

    const int h = bn / 192, ty = (bn >> 6) % 3;
    const int bb = bm >> 11, s0 = bm & 2047;
    if (ty < 2) {   // Q,K: contiguous [s][d] rows
        unsigned short* plane = qkvh + (((size_t)(bb * NH + h) * 3 + ty) * SEQ) * DH;
        const int s = t >> 1, hf = (t & 1) * 32;
        unsigned short* dst = plane + (size_t)(s0 + s) * DH + hf;
        #pragma unroll
        for (int k8 = 0; k8 < 4; ++k8)
            *(short8*)&dst[k8 * 8] = *(const short8*)&Tr[s * 72 + hf + k8 * 8];
    } else {        // V: transposed packed [d][s] stores
        const int d = t >> 2, pp = t & 3;
        unsigned short* vrow = vT + ((size_t)(bb * NH + h) * DH + d) * SEQ + s0 + pp * 32;
        #pragma unroll
        for (int k8 = 0; k8 < 4; ++k8) {
            alignas(16) unsigned short tmp[8];
            #pragma unroll
            for (int k = 0; k < 8; ++k) tmp[k] = Tr[(pp * 32 + k8 * 8 + k) * 72 + d];
            *(short8*)&vrow[k8 * 8] = *(short8*)tmp;
        }
    }
    __syncthreads();   // protect Tr/SM before next tile restages
}

// ---- phase 2: one (bh, 16-query) attention tile ----
__device__ __forceinline__ void attn_tile(int bh, int qt,
        const unsigned short* __restrict__ qkvh, const unsigned short* __restrict__ vT,
        const int* __restrict__ pad, unsigned short* __restrict__ Yb,
        char* smemc, int t) {
    const int b = bh >> 3, h = bh & 7;
    const int i0 = qt * QT, kb = i0 - HALF;
    const int lane = t & 63, w = t >> 6;
    const int lr = lane & 15, lg = lane >> 4;
    float* Sc = (float*)smemc;

    const unsigned short* Qg = qkvh + ((size_t)bh * 3 + 0) * SEQ * DH;
    const unsigned short* Kg = qkvh + ((size_t)bh * 3 + 1) * SEQ * DH;
    const unsigned short* vTg = vT + (size_t)bh * DH * SEQ;
    const int* padb = pad + b * SEQ;

    short8 qf[2];
    #pragma unroll
    for (int kk = 0; kk < 2; ++kk)
        qf[kk] = *(const short8*)&Qg[(size_t)(i0 + lr) * DH + kk * 32 + lg * 8];

    const int k0 = w * 16;
    #pragma unroll
    for (int c = 0; c < 5; ++c) {
        const int nc = (c < 4) ? 64 : 16;
        if (k0 < nc) {
            const int jl = c * 64 + k0 + lr;
            const int j = kb + jl;
            const int jc = j < 0 ? 0 : (j > SEQ - 1 ? SEQ - 1 : j);
            const int kv = (j >= 0 && j < SEQ) ? padb[j] : 0;
            f32x4 a0 = (f32x4){0.f, 0.f, 0.f, 0.f};
            #pragma unroll
            for (int kk = 0; kk < 2; ++kk) {
                const short8 bfr = *(const short8*)&Kg[(size_t)jc * DH + kk * 32 + lg * 8];
                a0 = __builtin_amdgcn_mfma_f32_16x16x32_bf16(qf[kk], bfr, a0, 0, 0, 0);
            }
            #pragma unroll
            for (int r = 0; r < 4; ++r) {
                const int q0 = lg * 4 + r;
                const bool ok = kv && (jl >= q0) && (jl <= q0 + 2 * HALF);
                Sc[q0 * SCS + jl] = ok ? a0[r] * 0.125f : -1e30f;
            }
        }
    }
    __syncthreads();

    for (int r = w; r < QT; r += 4) {
        float* row = &Sc[r * SCS];
        unsigned short* prow = (unsigned short*)row;
        if (!padb[i0 + r]) {
            #pragma unroll
            for (int u = 0; u < 5; ++u) {
                const int jl = lane + 64 * u;
                if (jl < KW) prow[jl] = 0;
            }
            if (lane >= 16 && lane < 32) prow[256 + lane] = 0;
            continue;
        }
        float v[5];
        float mx = -1e30f;
        #pragma unroll
        for (int u = 0; u < 5; ++u) {
            const int jl = lane + 64 * u;
            v[u] = (jl < KW) ? row[jl] : -1e30f;
            mx = fmaxf(mx, v[u]);
        }
        #pragma unroll
        for (int off = 32; off; off >>= 1) mx = fmaxf(mx, __shfl_xor(mx, off));
        float s = 0.f;
        #pragma unroll
        for (int u = 0; u < 5; ++u) { v[u] = __expf(v[u] - mx); s += v[u]; }
        #pragma unroll
        for (int off = 32; off; off >>= 1) s += __shfl_xor(s, off);
        const float inv = 1.f / s;
        asm volatile("" ::: "memory");
        #pragma unroll
        for (int u = 0; u < 5; ++u) {
            const int jl = lane + 64 * u;
            if (jl < KW) prow[jl] = f2bf(v[u] * inv);
        }
        if (lane >= 16 && lane < 32) prow[256 + lane] = 0;
    }
    __syncthreads();

    f32x4 o0 = (f32x4){0.f, 0.f, 0.f, 0.f};
    const unsigned short* PbU = (const unsigned short*)Sc;
    const int d0 = w * 16 + lr;
    #pragma unroll
    for (int c = 0; c < 5; ++c) {
        const int nkk = (c < 4) ? 2 : 1;
        #pragma unroll
        for (int kk = 0; kk < nkk; ++kk) {
            int j0 = kb + c * 64 + kk * 32 + lg * 8;
            j0 = j0 < 0 ? 0 : (j0 > SEQ - 8 ? SEQ - 8 : j0);
            const short8 vf = *(const short8*)&vTg[(size_t)d0 * SEQ + j0];
            const short8 pf = *(const short8*)&PbU[lr * (SCS * 2) + c * 64 + kk * 32 + lg * 8];
            o0 = __builtin_amdgcn_mfma_f32_16x16x32_bf16(pf, vf, o0, 0, 0, 0);
        }
    }

    #pragma unroll
    for (int r = 0; r < 4; ++r)
        Yb[(size_t)(b * SEQ + i0 + lg * 4 + r) * EMB + h * DH + d0] = f2bf(o0[r]);
    __syncthreads();   // protect Sc before next tile rewrites scores
}

// ---- phase 3: one 64x64 out-GEMM tile ----
__device__ __forceinline__ void out_tile(int bm, int bn,
        const unsigned short* __restrict__ A, const unsigned short* __restrict__ B,
        const float* __restrict__ bias, float* __restrict__ C,
        char* smemc, int t) {
    constexpr int BM = 64, BN = 64, BK = 64;
    unsigned short* As = (unsigned short*)smemc;
    unsigned short* Bs = As + BM * BK;
    const int lane = t & 63, wid = t >> 6;
    const int wr = wid >> 1, wc = wid & 1;
    const int lr = lane & 15, lg = lane >> 4;

    f32x4 acc[2][2];
    #pragma unroll
    for (int m = 0; m < 2; ++m)
        #pragma unroll
        for (int n = 0; n < 2; ++n)
            acc[m][n] = (f32x4){0.f, 0.f, 0.f, 0.f};

    for (int kt = 0; kt < DIM; kt += BK) {
        #pragma unroll
        for (int off = 0; off < BM * BK; off += 2048) {
            const int e = off + t * 8, r = e >> 6, c4 = (e & 63) >> 3;
            const int gc = (c4 ^ (r & 7)) << 3;
            gload_lds16(A + (size_t)(bm + r) * DIM + kt + gc, &As[e]);
        }
        #pragma unroll
        for (int off = 0; off < BN * BK; off += 2048) {
            const int e = off + t * 8, r = e >> 6, c4 = (e & 63) >> 3;
            const int gc = (c4 ^ (r & 7)) << 3;
            gload_lds16(B + (size_t)(bn + r) * DIM + kt + gc, &Bs[e]);
        }
        __syncthreads();
        short8 af[2][2], bf[2][2];
        #pragma unroll
        for (int kk = 0; kk < 2; ++kk) {
            #pragma unroll
            for (int m = 0; m < 2; ++m) {
                const int row = wr * 32 + m * 16 + lr;
                af[kk][m] = *(const short8*)&As[row * BK + (((kk * 4 + lg) ^ (row & 7)) << 3)];
            }
            #pragma unroll
            for (int n = 0; n < 2; ++n) {
                const int row = wc * 32 + n * 16 + lr;
                bf[kk][n] = *(const short8*)&Bs[row * BK + (((kk * 4 + lg) ^ (row & 7)) << 3)];
            }
        }
        #pragma unroll
        for (int kk = 0; kk < 2; ++kk)
            #pragma unroll
            for (int m = 0; m < 2; ++m)
                #pragma unroll
                for (int n = 0; n < 2; ++n)
                    acc[m][n] = __builtin_amdgcn_mfma_f32_16x16x32_bf16(af[kk][m], bf[kk][n], acc[m][n], 0, 0, 0);
        __syncthreads();
    }

    const int orow = bm + wr * 32 + lg * 4;
    const int oc0 = bn + wc * 32 + lr;
    #pragma unroll
    for (int m = 0; m < 2; ++m)
        #pragma unroll
        for (int n = 0; n < 2; ++n) {
            const int col = oc0 + n * 16;
            const float bv = bias[col];
            #pragma unroll
            for (int r = 0; r < 4; ++r)
                C[(size_t)(orow + m * 16 + r) * EMB + col] = acc[m][n][r] + bv;
        }
}

// ---- the whole pipeline, one launch ----
__global__ __launch_bounds__(256, 2)
void mega(const float* __restrict__ x, const int* __restrict__ pad,
          const float* __restrict__ wqkv_f, const float* __restrict__ bqkv,
          const float* __restrict__ wo_f, const float* __restrict__ bo,
          float* __restrict__ out,
          unsigned short* __restrict__ qkvh, unsigned short* __restrict__ vT,
          unsigned short* __restrict__ cvtbase, unsigned* __restrict__ counter) {
    __shared__ __align__(16) char smem[24576];
    const int bid = blockIdx.x, t = threadIdx.x;

    unsigned short* xb    = cvtbase;              // [4096,512]  bf16
    unsigned short* wqkvb = cvtbase + 2097152;    // [1536,512]  bf16
    unsigned short* wob   = cvtbase + 2883584;    // [512,512]   bf16
    unsigned short* Yb    = xb;                   // xb dead after phase 1

    // phase 0: f32 -> bf16 conversions (x, Wqkv, Wo)
    for (int i = bid * 256 + t; i < 786432; i += GRID * 256) {
        const float* src; int base;
        if (i < 524288)      { src = x;      base = 0; }
        else if (i < 720896) { src = wqkv_f; base = 524288; }
        else                 { src = wo_f;   base = 720896; }
        float4 v = ((const float4*)src)[i - base];
        ((ushort4*)cvtbase)[i] = make_ushort4(f2bf(v.x), f2bf(v.y), f2bf(v.z), f2bf(v.w));
    }
    grid_barrier(counter, GRID);

    // phase 1: qkv projection, 768 tiles of 128x64
    for (int tile = bid; tile < 768; tile += GRID)
        qkv_tile((tile / 24) * 128, (tile % 24) * 64, xb, wqkvb, bqkv, qkvh, vT, smem, t);
    grid_barrier(counter, 2 * GRID);

    // phase 2: windowed attention, 2048 tiles (exactly 4 per block)
    for (int tile = bid; tile < 2048; tile += GRID)
        attn_tile(tile >> 7, tile & 127, qkvh, vT, pad, Yb, smem, t);
    grid_barrier(counter, 3 * GRID);

    // phase 3: output projection, 512 tiles of 64x64 (exactly 1 per block)
    out_tile((bid >> 3) * 64, (bid & 7) * 64, Yb, wob, bo, out, smem, t);
}

extern "C" void kernel_launch(void* const* d_in, const int* in_sizes, int n_in,
                              void* d_out, int out_size, void* d_ws, size_t ws_size,
                              hipStream_t stream) {
    const float* x    = (const float*)d_in[0];
    const int*   pad  = (const int*)d_in[1];
    const float* Wqkv = (const float*)d_in[2];
    const float* bqkv = (const float*)d_in[3];
    const float* Wo   = (const float*)d_in[4];
    const float* bo   = (const float*)d_in[5];
    float* out = (float*)d_out;

    char* p = (char*)d_ws;
    unsigned short* qkvh    = (unsigned short*)p;                   // 12.6 MB (Q,K planes)
    unsigned short* vT      = (unsigned short*)(p + 12582912);      // 4 MB
    unsigned short* cvtbase = (unsigned short*)(p + 16777216);      // 6 MB (xb|wqkvb|wob)
    unsigned*       counter = (unsigned*)(p + 23068672);

    hipMemsetAsync(counter, 0, 64, stream);
    mega<<<dim3(GRID), dim3(256), 0, stream>>>(x, pad, Wqkv, bqkv, Wo, bo,
                                               out, qkvh, vT, cvtbase, counter);
}

// Round 10
// 56.718 us; speedup vs baseline: 4.3554x; 3.5570x over previous
//
#include <hip/hip_runtime.h>

#define NH   8
#define SEQ  2048
#define DIM  512
#define EMB  512
#define DH   64
#define HALF 128
#define QT   16
#define KW   272          // QT + 2*HALF
#define SCS  276          // Sc row stride (f32)

typedef __attribute__((ext_vector_type(8))) short short8;
typedef __attribute__((ext_vector_type(4))) float f32x4;

__device__ __forceinline__ unsigned short f2bf(float f) {
    unsigned int u = __float_as_uint(f);
    return (unsigned short)((u + 0x7fffu + ((u >> 16) & 1u)) >> 16);
}

// packed f32x2 -> bf16x2 (RNE), single HW instruction on gfx950
__device__ __forceinline__ unsigned cvtpk(float lo, float hi) {
    unsigned r;
    asm("v_cvt_pk_bf16_f32 %0, %1, %2" : "=v"(r) : "v"(lo), "v"(hi));
    return r;
}

__device__ __forceinline__ void gload_lds16(const void* g, void* l) {
    __builtin_amdgcn_global_load_lds((__attribute__((address_space(1))) void*)g,
                                     (__attribute__((address_space(3))) void*)l,
                                     16, 0, 0);
}

// qkv projection, f32 inputs converted inline during staging.
// 128x64 tiles, BK=64, 768 blocks, XCD-swizzled. Q,K -> qkvh[b][h][ty][s][d]
// packed; V -> vT[b][h][d][s] packed.
__global__ __launch_bounds__(256)
void gemm_qkv(const float* __restrict__ A, const float* __restrict__ B,
              const float* __restrict__ bias, unsigned short* __restrict__ qkvh,
              unsigned short* __restrict__ vT) {
    constexpr int BM = 128, BN = 64, BK = 64;
    __shared__ unsigned short As[BM * BK];   // [128][64] swizzled
    __shared__ unsigned short Bs[BN * BK];   // [64][64]  swizzled
    const int bid = blockIdx.x;
    const int wg = (bid & 7) * 96 + (bid >> 3);     // XCD-local A panels
    const int bm = (wg / 24) * BM, bn = (wg % 24) * BN;
    const int t = threadIdx.x, lane = t & 63, wid = t >> 6;
    const int wr = wid >> 1, wc = wid & 1;
    const int lr = lane & 15, lg = lane >> 4;

    f32x4 acc[4][2];
    #pragma unroll
    for (int m = 0; m < 4; ++m)
        #pragma unroll
        for (int n = 0; n < 2; ++n)
            acc[m][n] = (f32x4){0.f, 0.f, 0.f, 0.f};

    for (int kt = 0; kt < DIM; kt += BK) {
        // stage A: linear f32 reads, cvt_pk, swizzled b128 LDS writes
        #pragma unroll
        for (int i = 0; i < 4; ++i) {
            const int c = t + 256 * i, r = c >> 3, c8 = c & 7;
            const float4* src = (const float4*)(A + (size_t)(bm + r) * DIM + kt + c8 * 8);
            const float4 v0 = src[0], v1 = src[1];
            const uint4 pk = make_uint4(cvtpk(v0.x, v0.y), cvtpk(v0.z, v0.w),
                                        cvtpk(v1.x, v1.y), cvtpk(v1.z, v1.w));
            *(uint4*)&As[r * 64 + ((c8 ^ (r & 7)) << 3)] = pk;
        }
        #pragma unroll
        for (int i = 0; i < 2; ++i) {
            const int c = t + 256 * i, r = c >> 3, c8 = c & 7;
            const float4* src = (const float4*)(B + (size_t)(bn + r) * DIM + kt + c8 * 8);
            const float4 v0 = src[0], v1 = src[1];
            const uint4 pk = make_uint4(cvtpk(v0.x, v0.y), cvtpk(v0.z, v0.w),
                                        cvtpk(v1.x, v1.y), cvtpk(v1.z, v1.w));
            *(uint4*)&Bs[r * 64 + ((c8 ^ (r & 7)) << 3)] = pk;
        }
        __syncthreads();
        short8 af[2][4], bf[2][2];
        #pragma unroll
        for (int kk = 0; kk < 2; ++kk) {
            #pragma unroll
            for (int m = 0; m < 4; ++m) {
                const int row = wr * 64 + m * 16 + lr;
                af[kk][m] = *(const short8*)&As[row * 64 + (((kk * 4 + lg) ^ (row & 7)) << 3)];
            }
            #pragma unroll
            for (int n = 0; n < 2; ++n) {
                const int row = wc * 32 + n * 16 + lr;
                bf[kk][n] = *(const short8*)&Bs[row * 64 + (((kk * 4 + lg) ^ (row & 7)) << 3)];
            }
        }
        #pragma unroll
        for (int kk = 0; kk < 2; ++kk)
            #pragma unroll
            for (int m = 0; m < 4; ++m)
                #pragma unroll
                for (int n = 0; n < 2; ++n)
                    acc[m][n] = __builtin_amdgcn_mfma_f32_16x16x32_bf16(af[kk][m], bf[kk][n], acc[m][n], 0, 0, 0);
        __syncthreads();
    }

    // epilogue: acc -> Tr[128][72] bf16 (reuse As/Bs), then packed stores
    unsigned short* Tr = As;
    #pragma unroll
    for (int n = 0; n < 2; ++n) {
        const int cl = wc * 32 + n * 16 + lr;
        const float bv = bias[bn + cl];
        #pragma unroll
        for (int m = 0; m < 4; ++m)
            #pragma unroll
            for (int r = 0; r < 4; ++r)
                Tr[(wr * 64 + m * 16 + lg * 4 + r) * 72 + cl] = f2bf(acc[m][n][r] + bv);
    }
    __syncthreads();

    const int h = bn / 192, ty = (bn >> 6) % 3;
    const int bb = bm >> 11, s0 = bm & 2047;
    if (ty < 2) {   // Q,K: contiguous [s][d] rows
        unsigned short* plane = qkvh + (((size_t)(bb * NH + h) * 3 + ty) * SEQ) * DH;
        const int s = t >> 1, hf = (t & 1) * 32;
        unsigned short* dst = plane + (size_t)(s0 + s) * DH + hf;
        #pragma unroll
        for (int k8 = 0; k8 < 4; ++k8)
            *(short8*)&dst[k8 * 8] = *(const short8*)&Tr[s * 72 + hf + k8 * 8];
    } else {        // V: transposed packed [d][s] stores
        const int d = t >> 2, pp = t & 3;
        unsigned short* vrow = vT + ((size_t)(bb * NH + h) * DH + d) * SEQ + s0 + pp * 32;
        #pragma unroll
        for (int k8 = 0; k8 < 4; ++k8) {
            alignas(16) unsigned short tmp[8];
            #pragma unroll
            for (int k = 0; k < 8; ++k) tmp[k] = Tr[(pp * 32 + k8 * 8 + k) * 72 + d];
            *(short8*)&vrow[k8 * 8] = *(short8*)tmp;
        }
    }
}

// MFMA windowed attention, LDS-minimal (unchanged from R7 + XCD swizzle).
__global__ __launch_bounds__(256)
void attn_mfma(const unsigned short* __restrict__ qkvh,
               const unsigned short* __restrict__ vT,
               const int* __restrict__ pad,
               unsigned short* __restrict__ Yb) {
    const int bid = blockIdx.x;
    const int wg = (bid & 7) * 256 + (bid >> 3);     // XCD-local K/V planes
    const int bh = wg >> 7, qt = wg & 127;
    const int b = bh >> 3, h = bh & 7;
    const int i0 = qt * QT, kb = i0 - HALF;
    const int t = threadIdx.x, lane = t & 63, w = t >> 6;
    const int lr = lane & 15, lg = lane >> 4;

    __shared__ float Sc[QT * SCS];

    const unsigned short* Qg = qkvh + ((size_t)bh * 3 + 0) * SEQ * DH;
    const unsigned short* Kg = qkvh + ((size_t)bh * 3 + 1) * SEQ * DH;
    const unsigned short* vTg = vT + (size_t)bh * DH * SEQ;
    const int* padb = pad + b * SEQ;

    short8 qf[2];
    #pragma unroll
    for (int kk = 0; kk < 2; ++kk)
        qf[kk] = *(const short8*)&Qg[(size_t)(i0 + lr) * DH + kk * 32 + lg * 8];

    const int k0 = w * 16;
    #pragma unroll
    for (int c = 0; c < 5; ++c) {
        const int nc = (c < 4) ? 64 : 16;
        if (k0 < nc) {
            const int jl = c * 64 + k0 + lr;
            const int j = kb + jl;
            const int jc = j < 0 ? 0 : (j > SEQ - 1 ? SEQ - 1 : j);
            const int kv = (j >= 0 && j < SEQ) ? padb[j] : 0;
            f32x4 a0 = (f32x4){0.f, 0.f, 0.f, 0.f};
            #pragma unroll
            for (int kk = 0; kk < 2; ++kk) {
                const short8 bfr = *(const short8*)&Kg[(size_t)jc * DH + kk * 32 + lg * 8];
                a0 = __builtin_amdgcn_mfma_f32_16x16x32_bf16(qf[kk], bfr, a0, 0, 0, 0);
            }
            #pragma unroll
            for (int r = 0; r < 4; ++r) {
                const int q0 = lg * 4 + r;
                const bool ok = kv && (jl >= q0) && (jl <= q0 + 2 * HALF);
                Sc[q0 * SCS + jl] = ok ? a0[r] * 0.125f : -1e30f;
            }
        }
    }
    __syncthreads();

    for (int r = w; r < QT; r += 4) {
        float* row = &Sc[r * SCS];
        unsigned short* prow = (unsigned short*)row;
        if (!padb[i0 + r]) {
            #pragma unroll
            for (int u = 0; u < 5; ++u) {
                const int jl = lane + 64 * u;
                if (jl < KW) prow[jl] = 0;
            }
            if (lane >= 16 && lane < 32) prow[256 + lane] = 0;
            continue;
        }
        float v[5];
        float mx = -1e30f;
        #pragma unroll
        for (int u = 0; u < 5; ++u) {
            const int jl = lane + 64 * u;
            v[u] = (jl < KW) ? row[jl] : -1e30f;
            mx = fmaxf(mx, v[u]);
        }
        #pragma unroll
        for (int off = 32; off; off >>= 1) mx = fmaxf(mx, __shfl_xor(mx, off));
        float s = 0.f;
        #pragma unroll
        for (int u = 0; u < 5; ++u) { v[u] = __expf(v[u] - mx); s += v[u]; }
        #pragma unroll
        for (int off = 32; off; off >>= 1) s += __shfl_xor(s, off);
        const float inv = 1.f / s;
        asm volatile("" ::: "memory");
        #pragma unroll
        for (int u = 0; u < 5; ++u) {
            const int jl = lane + 64 * u;
            if (jl < KW) prow[jl] = f2bf(v[u] * inv);
        }
        if (lane >= 16 && lane < 32) prow[256 + lane] = 0;
    }
    __syncthreads();

    f32x4 o0 = (f32x4){0.f, 0.f, 0.f, 0.f};
    const unsigned short* PbU = (const unsigned short*)Sc;
    const int d0 = w * 16 + lr;
    #pragma unroll
    for (int c = 0; c < 5; ++c) {
        const int nkk = (c < 4) ? 2 : 1;
        #pragma unroll
        for (int kk = 0; kk < nkk; ++kk) {
            int j0 = kb + c * 64 + kk * 32 + lg * 8;
            j0 = j0 < 0 ? 0 : (j0 > SEQ - 8 ? SEQ - 8 : j0);
            const short8 vf = *(const short8*)&vTg[(size_t)d0 * SEQ + j0];
            const short8 pf = *(const short8*)&PbU[lr * (SCS * 2) + c * 64 + kk * 32 + lg * 8];
            o0 = __builtin_amdgcn_mfma_f32_16x16x32_bf16(pf, vf, o0, 0, 0, 0);
        }
    }

    #pragma unroll
    for (int r = 0; r < 4; ++r)
        Yb[(size_t)(b * SEQ + i0 + lg * 4 + r) * EMB + h * DH + d0] = f2bf(o0[r]);
}

// out = Yb(bf16) @ Wo(f32, converted inline)^T + bo. 64x64 tiles, 512 blocks.
__global__ __launch_bounds__(256)
void gemm_out(const unsigned short* __restrict__ A, const float* __restrict__ B,
              const float* __restrict__ bias, float* __restrict__ C) {
    constexpr int BM = 64, BN = 64, BK = 64;
    __shared__ unsigned short As[BM * BK];
    __shared__ unsigned short Bs[BN * BK];
    const int bid = blockIdx.x;
    const int wg = (bid & 7) * 64 + (bid >> 3);      // XCD-local A panels
    const int bm = (wg >> 3) * BM, bn = (wg & 7) * BN;
    const int t = threadIdx.x, lane = t & 63, wid = t >> 6;
    const int wr = wid >> 1, wc = wid & 1;
    const int lr = lane & 15, lg = lane >> 4;

    f32x4 acc[2][2];
    #pragma unroll
    for (int m = 0; m < 2; ++m)
        #pragma unroll
        for (int n = 0; n < 2; ++n)
            acc[m][n] = (f32x4){0.f, 0.f, 0.f, 0.f};

    for (int kt = 0; kt < DIM; kt += BK) {
        // A (bf16): global_load_lds with source pre-swizzle
        #pragma unroll
        for (int off = 0; off < BM * BK; off += 2048) {
            const int e = off + t * 8, r = e >> 6, c4 = (e & 63) >> 3;
            const int gc = (c4 ^ (r & 7)) << 3;
            gload_lds16(A + (size_t)(bm + r) * EMB + kt + gc, &As[e]);
        }
        // B (f32 Wo): reg-staged cvt_pk, swizzled LDS writes
        #pragma unroll
        for (int i = 0; i < 2; ++i) {
            const int c = t + 256 * i, r = c >> 3, c8 = c & 7;
            const float4* src = (const float4*)(B + (size_t)(bn + r) * DIM + kt + c8 * 8);
            const float4 v0 = src[0], v1 = src[1];
            const uint4 pk = make_uint4(cvtpk(v0.x, v0.y), cvtpk(v0.z, v0.w),
                                        cvtpk(v1.x, v1.y), cvtpk(v1.z, v1.w));
            *(uint4*)&Bs[r * 64 + ((c8 ^ (r & 7)) << 3)] = pk;
        }
        __syncthreads();
        short8 af[2][2], bf[2][2];
        #pragma unroll
        for (int kk = 0; kk < 2; ++kk) {
            #pragma unroll
            for (int m = 0; m < 2; ++m) {
                const int row = wr * 32 + m * 16 + lr;
                af[kk][m] = *(const short8*)&As[row * BK + (((kk * 4 + lg) ^ (row & 7)) << 3)];
            }
            #pragma unroll
            for (int n = 0; n < 2; ++n) {
                const int row = wc * 32 + n * 16 + lr;
                bf[kk][n] = *(const short8*)&Bs[row * BK + (((kk * 4 + lg) ^ (row & 7)) << 3)];
            }
        }
        #pragma unroll
        for (int kk = 0; kk < 2; ++kk)
            #pragma unroll
            for (int m = 0; m < 2; ++m)
                #pragma unroll
                for (int n = 0; n < 2; ++n)
                    acc[m][n] = __builtin_amdgcn_mfma_f32_16x16x32_bf16(af[kk][m], bf[kk][n], acc[m][n], 0, 0, 0);
        __syncthreads();
    }

    const int orow = bm + wr * 32 + lg * 4;
    const int oc0 = bn + wc * 32 + lr;
    #pragma unroll
    for (int m = 0; m < 2; ++m)
        #pragma unroll
        for (int n = 0; n < 2; ++n) {
            const int col = oc0 + n * 16;
            const float bv = bias[col];
            #pragma unroll
            for (int r = 0; r < 4; ++r)
                C[(size_t)(orow + m * 16 + r) * EMB + col] = acc[m][n][r] + bv;
        }
}

extern "C" void kernel_launch(void* const* d_in, const int* in_sizes, int n_in,
                              void* d_out, int out_size, void* d_ws, size_t ws_size,
                              hipStream_t stream) {
    const float* x    = (const float*)d_in[0];
    const int*   pad  = (const int*)d_in[1];
    const float* Wqkv = (const float*)d_in[2];
    const float* bqkv = (const float*)d_in[3];
    const float* Wo   = (const float*)d_in[4];
    const float* bo   = (const float*)d_in[5];
    float* out = (float*)d_out;

    char* p = (char*)d_ws;
    unsigned short* qkvh = (unsigned short*)p;                   // 12.6 MB (Q,K planes)
    unsigned short* vT   = (unsigned short*)(p + 12582912);      // 4 MB
    unsigned short* Yb   = (unsigned short*)(p + 16777216);      // 4 MB

    dim3 blk(256);
    gemm_qkv<<<dim3(768), blk, 0, stream>>>(x, Wqkv, bqkv, qkvh, vT);
    attn_mfma<<<dim3(2048), blk, 0, stream>>>(qkvh, vT, pad, Yb);
    gemm_out<<<dim3(512), blk, 0, stream>>>(Yb, Wo, bo, out);
}